// Round 1
// baseline (4320.094 us; speedup 1.0000x reference)
//
#include <hip/hip_runtime.h>

#define B_  64
#define T_  512
#define D_  64
#define U_  256
#define G4  1024   // 4*U

// ---------------------------------------------------------------------------
// Kernel 1: precompute xz[t*B+b][g] = bias[g] + sum_d x[b][t][d] * W[d][g]
// Tiled: each block computes 16 rows x 256 cols. ~4.3 GFLOP total.
// ---------------------------------------------------------------------------
__global__ __launch_bounds__(256) void xz_kernel(const float* __restrict__ x,
                                                 const float* __restrict__ W,
                                                 const float* __restrict__ bias,
                                                 float* __restrict__ xz) {
    __shared__ float xt[16][D_];
    const int g    = blockIdx.x * 256 + threadIdx.x;
    const int row0 = blockIdx.y * 16;

    // Stage 16 rows of x (each row = x[b][t][:], row index = t*B + b)
    #pragma unroll
    for (int j = 0; j < 4; ++j) {
        int e = threadIdx.x + 256 * j;          // 0..1023
        int r = e >> 6, d = e & 63;
        int row = row0 + r;
        int t = row >> 6, b = row & 63;         // row = t*64 + b
        xt[r][d] = x[((size_t)b * T_ + t) * D_ + d];
    }
    __syncthreads();

    float acc[16];
    #pragma unroll
    for (int r = 0; r < 16; ++r) acc[r] = 0.f;

    for (int d = 0; d < D_; ++d) {
        float w = W[(size_t)d * G4 + g];        // coalesced across g
        #pragma unroll
        for (int r = 0; r < 16; ++r) acc[r] += xt[r][d] * w;
    }

    float bg = bias[g];
    #pragma unroll
    for (int r = 0; r < 16; ++r)
        xz[(size_t)(row0 + r) * G4 + g] = acc[r] + bg;
}

// ---------------------------------------------------------------------------
// Kernel 2: sequential LSTM scan. One workgroup (1024 threads) per batch
// element. Thread g owns gate column g; threads u<256 own persistent c[u].
// ---------------------------------------------------------------------------
__device__ __forceinline__ float sigmoidf_(float z) {
    return 1.f / (1.f + __expf(-z));
}

template <bool PRE>
__global__ __launch_bounds__(1024) void lstm_kernel(
        const float* __restrict__ x,
        const float* __restrict__ W,
        const float* __restrict__ Um,
        const float* __restrict__ bias,
        const float* __restrict__ dw,
        const float* __restrict__ dbp,
        const float* __restrict__ xz,
        float* __restrict__ out) {
    __shared__ float h_s[U_];
    __shared__ float z_s[G4];
    __shared__ float pd_s[U_];

    const int g = threadIdx.x;      // 0..1023 gate column
    const int b = blockIdx.x;       // batch element

    float bg = 0.f;
    if (!PRE) bg = bias[g];
    const float dwr = (g < U_) ? dw[g] : 0.f;
    const float db0 = dbp[0];

    float c = 0.f;                  // persistent cell state for u = g (g<256)
    if (g < U_) h_s[g] = 0.f;
    __syncthreads();

    const float* Ucol = Um + g;     // column g of U, row stride G4

    for (int t = 0; t < T_; ++t) {
        // ---- z_g = xz + h @ U  (column g) ----
        float acc0, acc1;
        if (PRE) {
            acc0 = xz[((size_t)t * B_ + b) * G4 + g];
            acc1 = 0.f;
        } else {
            acc0 = bg; acc1 = 0.f;
            const float* xrow = x + ((size_t)b * T_ + t) * D_;
            #pragma unroll 8
            for (int d = 0; d < D_; d += 2) {
                acc0 += xrow[d]     * W[(size_t)d       * G4 + g];
                acc1 += xrow[d + 1] * W[(size_t)(d + 1) * G4 + g];
            }
        }

        #pragma unroll 4
        for (int k = 0; k < U_; k += 4) {
            float4 h4 = *(const float4*)&h_s[k];    // uniform-address broadcast
            acc0 += h4.x * Ucol[(size_t)(k + 0) * G4];
            acc1 += h4.y * Ucol[(size_t)(k + 1) * G4];
            acc0 += h4.z * Ucol[(size_t)(k + 2) * G4];
            acc1 += h4.w * Ucol[(size_t)(k + 3) * G4];
        }
        z_s[g] = acc0 + acc1;
        __syncthreads();            // z ready

        // ---- gates + state update (threads u < 256) ----
        if (g < U_) {
            float zi = z_s[g];
            float zf = z_s[U_ + g];
            float zg = z_s[2 * U_ + g];
            float zo = z_s[3 * U_ + g];
            float ig = sigmoidf_(zi);
            float fg = sigmoidf_(zf);
            float gg = fmaxf(zg, 0.f);
            float og = sigmoidf_(zo);
            c = fg * c + ig * gg;
            float h = og * fmaxf(c, 0.f);
            h_s[g]  = h;
            pd_s[g] = h * dwr;
        }
        __syncthreads();            // h (and pd) ready

        // ---- dense output: sigma[b][t] = sum_u h[u]*dw[u] + db ----
        if (g < 64) {
            float s = pd_s[g] + pd_s[g + 64] + pd_s[g + 128] + pd_s[g + 192];
            #pragma unroll
            for (int off = 32; off > 0; off >>= 1)
                s += __shfl_down(s, off);
            if (g == 0) out[(size_t)b * T_ + t] = s + db0;
        }
    }
}

// ---------------------------------------------------------------------------
extern "C" void kernel_launch(void* const* d_in, const int* in_sizes, int n_in,
                              void* d_out, int out_size, void* d_ws, size_t ws_size,
                              hipStream_t stream) {
    const float* x    = (const float*)d_in[0];
    const float* W    = (const float*)d_in[1];
    const float* Um   = (const float*)d_in[2];
    const float* bias = (const float*)d_in[3];
    const float* dw   = (const float*)d_in[4];
    const float* db   = (const float*)d_in[5];
    float* out = (float*)d_out;

    const size_t need = (size_t)T_ * B_ * G4 * sizeof(float);   // 128 MiB
    if (ws_size >= need) {
        float* xz = (float*)d_ws;
        dim3 gridX(G4 / 256, (T_ * B_) / 16);
        xz_kernel<<<gridX, 256, 0, stream>>>(x, W, bias, xz);
        lstm_kernel<true><<<B_, 1024, 0, stream>>>(x, W, Um, bias, dw, db, xz, out);
    } else {
        lstm_kernel<false><<<B_, 1024, 0, stream>>>(x, W, Um, bias, dw, db, nullptr, out);
    }
}